// Round 8
// baseline (15276.701 us; speedup 1.0000x reference)
//
#include <hip/hip_runtime.h>
#include <hip/hip_bf16.h>
#include <stdint.h>
#include <stddef.h>

// Problem constants
#define B_ 4096
#define S_ 64
#define D_ 512
#define DEPTH_ 4

// ---------------------------------------------------------------------------
// R18 design = R17 (best known, 14157us) + one delta:
//  * gemm_bf16 goes 8-wave (512 threads), same 128^2 tile + same R17
//    prefetch (STAGE next -> counted vmcnt(4) -> raw barrier -> MFMA ->
//    raw barrier). Waves/CU 8 -> 16 (2 -> 4 per SIMD): scheduler always
//    has a runnable wave while others sit on vmcnt — attacks the residual
//    latency R17 left exposed. Per-wave: 4 loads/tile, acc[4][2] (32 VGPR).
//    LDS/grid/math order unchanged -> absmax unchanged.
//  * Locked per R10-R17: m97-lineage K-loop for big GEMMs (BK=64,
//    global_load_lds w=16, dbuf counted-vmcnt prefetch), small-GEMM
//    direct-B + swizzled sY (R14), split-K=4 g3 bf16 partials, X
//    ping-pong, grids >=512 blocks, no cross-block sync, no XCD swizzle.
//  * Failure modes mapped: R12 (TM<128 on big GEMM), R15 (1 wave/SIMD
//    full-width fusion), R16 (direct-global big GEMM).
// ---------------------------------------------------------------------------

typedef __attribute__((ext_vector_type(8))) __bf16 bf16x8;
typedef __attribute__((ext_vector_type(4))) float f32x4;
typedef __hip_bfloat16 bf16_t;

constexpr int SPLITZ = 4;   // g3 split-K partials

__device__ __forceinline__ void async_copy16(const void* g, void* lds) {
  __builtin_amdgcn_global_load_lds(
      (const __attribute__((address_space(1))) void*)g,
      (__attribute__((address_space(3))) void*)lds, 16, 0, 0);
}

__device__ __forceinline__ float bf2f(bf16_t h) { return __bfloat162float(h); }

// fold bf16 partial row-chunk into v[8]
__device__ __forceinline__ void fold_p(float v[8], const bf16_t* pz)
{
  alignas(16) bf16_t t[8];
  *(uint4*)t = *(const uint4*)pz;
#pragma unroll
  for (int i = 0; i < 8; ++i) v[i] += bf2f(t[i]);
}

// LayerNorm row math shared by the storers
__device__ __forceinline__ void ln_vals(const float v[8],
                                        const float* __restrict__ gamma,
                                        const float* __restrict__ beta,
                                        int lane, bf16_t o8[8])
{
  float s = 0.f, ss = 0.f;
#pragma unroll
  for (int i = 0; i < 8; ++i) { s += v[i]; ss += v[i] * v[i]; }
#pragma unroll
  for (int o = 32; o; o >>= 1) { s += __shfl_xor(s, o); ss += __shfl_xor(ss, o); }
  const float m   = s * (1.f / D_);
  const float inv = rsqrtf(ss * (1.f / D_) - m * m + 1e-5f);
  const int c0 = lane * 8;
  float g[8], b[8];
  *(float4*)&g[0] = *(const float4*)&gamma[c0];
  *(float4*)&g[4] = *(const float4*)&gamma[c0 + 4];
  *(float4*)&b[0] = *(const float4*)&beta[c0];
  *(float4*)&b[4] = *(const float4*)&beta[c0 + 4];
#pragma unroll
  for (int i = 0; i < 8; ++i)
    o8[i] = __float2bfloat16((v[i] - m) * inv * g[i] + b[i]);
}

// LN + plain row store (global Y rows)
__device__ __forceinline__ void ln_store(const float v[8],
                                         const float* __restrict__ gamma,
                                         const float* __restrict__ beta,
                                         bf16_t* yrow, int lane)
{
  alignas(16) bf16_t o8[8];
  ln_vals(v, gamma, beta, lane, o8);
  *(uint4*)&yrow[lane * 8] = *(const uint4*)o8;
}

// LN + XOR-swizzled LDS row store: elem ^= (row&7)<<3 (bank-spread for the
// stride-1024B ds_read_b128 in the K-loop; bijective within the row)
__device__ __forceinline__ void ln_store_swz(const float v[8],
                                             const float* __restrict__ gamma,
                                             const float* __restrict__ beta,
                                             bf16_t* srow, int row, int lane)
{
  alignas(16) bf16_t o8[8];
  ln_vals(v, gamma, beta, lane, o8);
  const int c0s = (lane * 8) ^ ((row & 7) << 3);
  *(uint4*)&srow[c0s] = *(const uint4*)o8;
}

// ---------------------------------------------------------------------------
// GEMM, 8 waves (512 thr), 2-phase dbuf prefetch: C = A @ Bt^T (+bias).
//   EPI 1: O[row*N+col]  = bf16(relu(acc+b))   (SPLITK==1)
//   EPI 2: O[z*M*N + row*N+col] = bf16(acc (+bias if z==0))
// Per-iter: STAGE(next) -> counted vmcnt(4) -> raw barrier -> MFMA ->
//           raw barrier. Wave (wm=wave&1, wn=wave>>1) owns 64x32 output.
// ---------------------------------------------------------------------------
template<int TM, int TN, int EPI, int SPLITK>
__launch_bounds__(512)
__global__ void gemm_bf16(const bf16_t* __restrict__ A,
                          const bf16_t* __restrict__ Bt,
                          const float* __restrict__ bias,
                          bf16_t* __restrict__ O,
                          int M, int N, int K)
{
  constexpr int BK  = 64;
  constexpr int WM  = TM / 2, WN = TN / 4;
  constexpr int NMI = WM / 16, NNI = WN / 16;
  constexpr int CA  = TM / 8, CB = TN / 8;   // 1KB chunks (8 rows of 128B)
  constexpr int BUF = (TM + TN) * BK;        // elems per stage buffer
  static_assert((CA + CB) / 8 == 4, "vmcnt(4) assumes 4 loads/wave/tile");
  static_assert(TM * TN <= BUF, "C tile must fit in one staging buffer");

  __shared__ __align__(16) bf16_t smem[2 * BUF];   // 64KB (2 blocks/CU cap)

  const int tid  = threadIdx.x;
  const int lane = tid & 63;
  const int wave = tid >> 6;          // 0..7
  const int wm   = wave & 1;          // 64-row half
  const int wn   = wave >> 1;         // 32-col quarter
  const int m0   = blockIdx.x * TM;
  const int n0   = blockIdx.y * TN;
  const int KS   = K / SPLITK;
  const int kbeg = blockIdx.z * KS;
  const int NI   = KS / BK;

  const int lr = lane >> 3;        // row within 1KB chunk (8 rows)
  const int lc = (lane & 7) * 8;   // bf16 col within row

  f32x4 acc[NMI][NNI];
#pragma unroll
  for (int mi = 0; mi < NMI; ++mi)
#pragma unroll
    for (int ni = 0; ni < NNI; ++ni)
      acc[mi][ni] = (f32x4){0.f, 0.f, 0.f, 0.f};

  // stage one BK-tile into buffer b (4 global_load_lds per wave, 8 waves)
  auto STAGE = [&](int k0, int b) {
    bf16_t* sA = smem + b * BUF;
    bf16_t* sB = sA + TM * BK;
#pragma unroll
    for (int c = wave; c < CA; c += 8)
      async_copy16(A + (size_t)(m0 + c * 8 + lr) * K + (k0 + lc),
                   (char*)sA + c * 1024);
#pragma unroll
    for (int c = wave; c < CB; c += 8)
      async_copy16(Bt + (size_t)(n0 + c * 8 + lr) * K + (k0 + lc),
                   (char*)sB + c * 1024);
  };

  STAGE(kbeg, 0);   // prologue: tile 0 in flight

  for (int i = 0; i < NI; ++i) {
    const int cur = i & 1;
    if (i + 1 < NI) {
      STAGE(kbeg + (i + 1) * BK, cur ^ 1);           // prefetch next tile
      asm volatile("s_waitcnt vmcnt(4)" ::: "memory"); // wait tile i only
    } else {
      asm volatile("s_waitcnt vmcnt(0)" ::: "memory");
    }
    __builtin_amdgcn_s_barrier();          // raw: no implicit vmcnt(0) drain
    __builtin_amdgcn_sched_barrier(0);

    const bf16_t* sA = smem + cur * BUF;
    const bf16_t* sB = sA + TM * BK;
#pragma unroll
    for (int kk = 0; kk < BK; kk += 32) {
      bf16x8 af[NMI], bfv[NNI];
#pragma unroll
      for (int mi = 0; mi < NMI; ++mi)
        af[mi] = *(const bf16x8*)&sA[(wm * WM + mi * 16 + (lane & 15)) * BK + kk + (lane >> 4) * 8];
#pragma unroll
      for (int ni = 0; ni < NNI; ++ni)
        bfv[ni] = *(const bf16x8*)&sB[(wn * WN + ni * 16 + (lane & 15)) * BK + kk + (lane >> 4) * 8];
#pragma unroll
      for (int mi = 0; mi < NMI; ++mi)
#pragma unroll
        for (int ni = 0; ni < NNI; ++ni)
          acc[mi][ni] = __builtin_amdgcn_mfma_f32_16x16x32_bf16(af[mi], bfv[ni], acc[mi][ni], 0, 0, 0);
    }
    // each wave's ds_reads have returned (lgkmcnt before MFMA) before here
    __builtin_amdgcn_sched_barrier(0);
    __builtin_amdgcn_s_barrier();          // protect buf before next STAGE
  }

  // Coalesced epilogue: round into LDS (reuse staging buffer), then
  // row-major uint4 stores. C/D layout (m89/m91): col=lane&15,
  // row=(lane>>4)*4 + r.
  bf16_t* sC = smem;
#pragma unroll
  for (int mi = 0; mi < NMI; ++mi) {
#pragma unroll
    for (int ni = 0; ni < NNI; ++ni) {
      const int col  = wn * WN + ni * 16 + (lane & 15);
      const int row0 = wm * WM + mi * 16 + ((lane >> 4) << 2);
      const float bv = (SPLITK == 1 || blockIdx.z == 0) ? bias[n0 + col] : 0.f;
#pragma unroll
      for (int r = 0; r < 4; ++r) {
        float v = acc[mi][ni][r] + bv;
        if constexpr (EPI == 1) v = v > 0.f ? v : 0.f;
        sC[(row0 + r) * TN + col] = __float2bfloat16(v);
      }
    }
  }
  __syncthreads();
  bf16_t* Ob = O + (EPI == 2 ? (size_t)blockIdx.z * M * N : (size_t)0);
#pragma unroll
  for (int p = 0; p < (TM * TN) / 4096; ++p) {   // 512 thr x 8 elems/pass
    const int chunk = p * 512 + tid;
    const int rr = chunk / (TN / 8);
    const int cc = (chunk % (TN / 8)) * 8;
    *(uint4*)&Ob[(size_t)(m0 + rr) * N + n0 + cc] = *(const uint4*)&sC[rr * TN + cc];
  }
}

// x = X + P1 (bf16 partial); write X; y = LN(x). 4 rows/block.
__global__ void ln_sum1_kernel(float* __restrict__ X,
                               const bf16_t* __restrict__ P,
                               const float* __restrict__ gamma,
                               const float* __restrict__ beta,
                               bf16_t* __restrict__ Y)
{
  const int row  = blockIdx.x * 4 + (threadIdx.x >> 6);
  const int lane = threadIdx.x & 63;
  const int c0 = lane * 8;
  float* xr = X + (size_t)row * D_;
  float v[8];
  *(float4*)&v[0] = *(const float4*)&xr[c0];
  *(float4*)&v[4] = *(const float4*)&xr[c0 + 4];
  fold_p(v, P + (size_t)row * D_ + c0);
  *(float4*)&xr[c0]     = *(const float4*)&v[0];
  *(float4*)&xr[c0 + 4] = *(const float4*)&v[4];
  ln_store(v, gamma, beta, Y + (size_t)row * D_, lane);
}

// ---------------------------------------------------------------------------
// Barrier-free K-loop for the small D x D GEMM (shared by lnfold/addln):
// A = swizzled sY (LDS, written once), B = direct global (L2-hot Wc panel).
// ---------------------------------------------------------------------------
__device__ __forceinline__ void small_gemm_loop(const bf16_t* __restrict__ sY,
                                                const bf16_t* __restrict__ Bt,
                                                int n0, int wave, int lane,
                                                f32x4 acc[2][2])
{
  const bf16_t* b0 = Bt + (size_t)(n0 + wave * 32 + (lane & 15)) * D_ + (lane >> 4) * 8;
  const bf16_t* b1 = b0 + (size_t)16 * D_;
  const int r0 = (lane & 15);
  const int r1 = 16 + (lane & 15);
  const int x0 = (r0 & 7) << 3;          // swizzle XOR for rows 0-15
  const int ka = (lane >> 4) * 8;
#pragma unroll
  for (int k0 = 0; k0 < D_; k0 += 32) {
    bf16x8 af0, af1, bv0, bv1;
    bv0 = *(const bf16x8*)&b0[k0];
    bv1 = *(const bf16x8*)&b1[k0];
    af0 = *(const bf16x8*)&sY[r0 * D_ + ((k0 + ka) ^ x0)];
    af1 = *(const bf16x8*)&sY[r1 * D_ + ((k0 + ka) ^ x0)];  // (r1&7)==(r0&7)
    acc[0][0] = __builtin_amdgcn_mfma_f32_16x16x32_bf16(af0, bv0, acc[0][0], 0, 0, 0);
    acc[0][1] = __builtin_amdgcn_mfma_f32_16x16x32_bf16(af0, bv1, acc[0][1], 0, 0, 0);
    acc[1][0] = __builtin_amdgcn_mfma_f32_16x16x32_bf16(af1, bv0, acc[1][0], 0, 0, 0);
    acc[1][1] = __builtin_amdgcn_mfma_f32_16x16x32_bf16(af1, bv1, acc[1][1], 0, 0, 0);
  }
}

// shared coalesced epilogue through sC (=sY reused) for the small GEMMs
__device__ __forceinline__ void small_gemm_epi(bf16_t* sC, bf16_t* __restrict__ O,
                                               const float* __restrict__ bias,
                                               const f32x4 acc[2][2],
                                               int m0, int n0, int wave, int lane,
                                               int tid)
{
  constexpr int TM = 32, TN = 128;
#pragma unroll
  for (int mi = 0; mi < 2; ++mi) {
#pragma unroll
    for (int ni = 0; ni < 2; ++ni) {
      const int col  = wave * 32 + ni * 16 + (lane & 15);
      const int row0 = mi * 16 + ((lane >> 4) << 2);
      const float bv = bias[n0 + col];
#pragma unroll
      for (int r = 0; r < 4; ++r)
        sC[(row0 + r) * TN + col] = __float2bfloat16(acc[mi][ni][r] + bv);
    }
  }
  __syncthreads();
#pragma unroll
  for (int p = 0; p < (TM * TN) / 2048; ++p) {   // 2 passes
    const int chunk = p * 256 + tid;
    const int rr = chunk / (TN / 8);
    const int cc = (chunk % (TN / 8)) * 8;
    *(uint4*)&O[(size_t)(m0 + rr) * D_ + n0 + cc] = *(const uint4*)&sC[rr * TN + cc];
  }
}

// ---------------------------------------------------------------------------
// Fused [x = Xin + sum_{z<4} PSPL; LN1; P1 = y@Wc + bc], layers 1..3.
// TM=32 rows, TN=128 cols; grid (B/32, 4) = 512 blocks, 256 thr.
// LDS: sY 32KB only. Two barriers total (post-prologue, pre-epilogue).
// blockIdx.y==0 writes Xout (ping-pong buffer, no race with Xin reads).
// ---------------------------------------------------------------------------
__launch_bounds__(256)
__global__ void lnfold_gemm(const float* __restrict__ Xin,
                            const bf16_t* __restrict__ P,
                            float* __restrict__ Xout,
                            const float* __restrict__ gamma,
                            const float* __restrict__ beta,
                            const bf16_t* __restrict__ Bt,   // WCT layer slice
                            const float* __restrict__ bias,  // BC layer slice
                            bf16_t* __restrict__ O)          // P1
{
  constexpr int TM = 32;
  __shared__ __align__(16) bf16_t sY[TM * D_];   // 32KB

  const int tid  = threadIdx.x;
  const int lane = tid & 63;
  const int wave = tid >> 6;
  const int m0   = blockIdx.x * TM;
  const int n0   = blockIdx.y * 128;
  const int c0   = lane * 8;

  // ---- prologue: fold partials + LN (swizzled store), 8 rows per wave ----
#pragma unroll
  for (int i = 0; i < 8; ++i) {
    const int row  = wave * 8 + i;
    const int grow = m0 + row;
    const float* xr = Xin + (size_t)grow * D_ + c0;
    float v[8];
    *(float4*)&v[0] = *(const float4*)&xr[0];
    *(float4*)&v[4] = *(const float4*)&xr[4];
#pragma unroll
    for (int z = 0; z < SPLITZ; ++z)
      fold_p(v, P + (size_t)z * B_ * D_ + (size_t)grow * D_ + c0);
    if (blockIdx.y == 0) {
      float* xo = Xout + (size_t)grow * D_ + c0;
      *(float4*)&xo[0] = *(const float4*)&v[0];
      *(float4*)&xo[4] = *(const float4*)&v[4];
    }
    ln_store_swz(v, gamma, beta, &sY[row * D_], row, lane);
  }
  __syncthreads();   // sY visible to all waves

  f32x4 acc[2][2];
#pragma unroll
  for (int mi = 0; mi < 2; ++mi)
#pragma unroll
    for (int ni = 0; ni < 2; ++ni)
      acc[mi][ni] = (f32x4){0.f, 0.f, 0.f, 0.f};

  small_gemm_loop(sY, Bt, n0, wave, lane, acc);

  __syncthreads();   // all sY reads done before reuse as sC
  small_gemm_epi(sY, O, bias, acc, m0, n0, wave, lane, tid);
}

// ---------------------------------------------------------------------------
// Fused step boundary + g1 (layer 0):
//  h = hsrc (+ fold PSPL if P); head(t-1) from h (if out, blockIdx.y==0);
//  x = emb_a + emb_b + h -> Xout (y==0); y = LN1_0(x) -> sY (swizzled);
//  P1 = y @ Wc0 + bc0.  Same geometry as lnfold_gemm.
// ---------------------------------------------------------------------------
__launch_bounds__(256)
__global__ void addln_gemm(const int* __restrict__ a_seq,
                           const int* __restrict__ b_seq,
                           const float* __restrict__ bit_emb,
                           const float* __restrict__ hsrc, int hstride,
                           const bf16_t* __restrict__ P,
                           float* __restrict__ Xout,
                           const float* __restrict__ gamma,
                           const float* __restrict__ beta,
                           const bf16_t* __restrict__ Bt,   // WCT layer 0
                           const float* __restrict__ bias,  // BC layer 0
                           bf16_t* __restrict__ O,          // P1
                           int t,
                           const float* __restrict__ hw,
                           const float* __restrict__ hb,
                           float* __restrict__ out)
{
  constexpr int TM = 32;
  __shared__ __align__(16) bf16_t sY[TM * D_];   // 32KB

  const int tid  = threadIdx.x;
  const int lane = tid & 63;
  const int wave = tid >> 6;
  const int m0   = blockIdx.x * TM;
  const int n0   = blockIdx.y * 128;
  const int c0   = lane * 8;

  const bool do_head = (out != nullptr) && (blockIdx.y == 0);
  float w[16];
  if (do_head) {
#pragma unroll
    for (int i = 0; i < 4; ++i)
      *(float4*)&w[i * 4] = *(const float4*)&hw[lane * 16 + i * 4];
  }

#pragma unroll
  for (int i = 0; i < 8; ++i) {
    const int row  = wave * 8 + i;
    const int grow = m0 + row;
    const int ai = a_seq[grow * S_ + t];
    const int bi = b_seq[grow * S_ + t];
    const float* pr = hsrc + (size_t)grow * hstride + c0;
    float p[8];
    *(float4*)&p[0] = *(const float4*)&pr[0];
    *(float4*)&p[4] = *(const float4*)&pr[4];
    if (P != nullptr) {
#pragma unroll
      for (int z = 0; z < SPLITZ; ++z)
        fold_p(p, P + (size_t)z * B_ * D_ + (size_t)grow * D_ + c0);
    }
    if (do_head) {
      float s0 = 0.f, s1 = 0.f;
#pragma unroll
      for (int j = 0; j < 8; ++j) { s0 += p[j] * w[2 * j]; s1 += p[j] * w[2 * j + 1]; }
#pragma unroll
      for (int o = 32; o; o >>= 1) { s0 += __shfl_xor(s0, o); s1 += __shfl_xor(s1, o); }
      if (lane == 0) {
        float* po = out + (size_t)grow * (S_ * 2) + (t - 1) * 2;
        po[0] = s0 + hb[0];
        po[1] = s1 + hb[1];
      }
    }
    float ea[8], eb[8], v[8];
    *(float4*)&ea[0] = *(const float4*)&bit_emb[ai * D_ + c0];
    *(float4*)&ea[4] = *(const float4*)&bit_emb[ai * D_ + c0 + 4];
    *(float4*)&eb[0] = *(const float4*)&bit_emb[bi * D_ + c0];
    *(float4*)&eb[4] = *(const float4*)&bit_emb[bi * D_ + c0 + 4];
#pragma unroll
    for (int j = 0; j < 8; ++j) v[j] = ea[j] + eb[j] + p[j];
    if (blockIdx.y == 0) {
      float* xo = Xout + (size_t)grow * D_ + c0;
      *(float4*)&xo[0] = *(const float4*)&v[0];
      *(float4*)&xo[4] = *(const float4*)&v[4];
    }
    ln_store_swz(v, gamma, beta, &sY[row * D_], row, lane);
  }
  __syncthreads();   // sY visible

  f32x4 acc[2][2];
#pragma unroll
  for (int mi = 0; mi < 2; ++mi)
#pragma unroll
    for (int ni = 0; ni < 2; ++ni)
      acc[mi][ni] = (f32x4){0.f, 0.f, 0.f, 0.f};

  small_gemm_loop(sY, Bt, n0, wave, lane, acc);

  __syncthreads();
  small_gemm_epi(sY, O, bias, acc, m0, n0, wave, lane, tid);
}

// Final head: h = X + P0..P3; logits[row, S-1, :] = h @ head_w + head_b.
__global__ void head_kernel(const float* __restrict__ X,
                            const bf16_t* __restrict__ P,
                            const float* __restrict__ hw,
                            const float* __restrict__ hb,
                            float* __restrict__ out, int t)
{
  const int row  = blockIdx.x * 4 + (threadIdx.x >> 6);
  const int lane = threadIdx.x & 63;
  const float* xr = X + (size_t)row * D_;
  const int c0 = lane * 8;
  float v[8];
  *(float4*)&v[0] = *(const float4*)&xr[c0];
  *(float4*)&v[4] = *(const float4*)&xr[c0 + 4];
#pragma unroll
  for (int z = 0; z < SPLITZ; ++z)
    fold_p(v, P + (size_t)z * B_ * D_ + (size_t)row * D_ + c0);
  float w[16];
#pragma unroll
  for (int i = 0; i < 4; ++i)
    *(float4*)&w[i * 4] = *(const float4*)&hw[lane * 16 + i * 4];
  float s0 = 0.f, s1 = 0.f;
#pragma unroll
  for (int i = 0; i < 8; ++i) { s0 += v[i] * w[2 * i]; s1 += v[i] * w[2 * i + 1]; }
#pragma unroll
  for (int o = 32; o; o >>= 1) { s0 += __shfl_xor(s0, o); s1 += __shfl_xor(s1, o); }
  if (lane == 0) {
    float* po = out + (size_t)row * (S_ * 2) + t * 2;
    po[0] = s0 + hb[0];
    po[1] = s1 + hb[1];
  }
}

// ---------------------------------------------------------------------------
// Prep kernels (run every launch; graph-safe)
// ---------------------------------------------------------------------------
__global__ void prep_wc(const float* __restrict__ qkv_w,
                        const float* __restrict__ out_w,
                        float* __restrict__ wc)
{
  const int n = blockIdx.x * 256 + threadIdx.x;
  const int k = blockIdx.y;
  const int l = blockIdx.z;
  const float* qrow = qkv_w + ((size_t)l * D_ + k) * (3 * D_) + 2 * D_;
  const float* ow   = out_w + (size_t)l * D_ * D_;
  float acc = 0.f;
  for (int j = 0; j < D_; ++j) acc += qrow[j] * ow[(size_t)j * D_ + n];
  wc[((size_t)l * D_ + k) * D_ + n] = acc;
}

__global__ void prep_bc(const float* __restrict__ qkv_b,
                        const float* __restrict__ out_w,
                        const float* __restrict__ out_b,
                        float* __restrict__ bc)
{
  const int l = blockIdx.x;
  const int n = threadIdx.x;
  const float* qb = qkv_b + (size_t)l * (3 * D_) + 2 * D_;
  const float* ow = out_w + (size_t)l * D_ * D_;
  float acc = out_b[(size_t)l * D_ + n];
  for (int j = 0; j < D_; ++j) acc += qb[j] * ow[(size_t)j * D_ + n];
  bc[(size_t)l * D_ + n] = acc;
}

// dst(C,R) bf16 = transpose(src(R,C) fp32), per-layer via blockIdx.z
__global__ void transpose_conv(const float* __restrict__ src,
                               bf16_t* __restrict__ dst, int R, int C)
{
  __shared__ float tile[32][33];
  const int l = blockIdx.z;
  const float* s = src + (size_t)l * R * C;
  bf16_t* d = dst + (size_t)l * R * C;
  const int c0 = blockIdx.x * 32, r0 = blockIdx.y * 32;
  const int tx = threadIdx.x, ty = threadIdx.y;
  tile[ty][tx] = s[(size_t)(r0 + ty) * C + (c0 + tx)];
  __syncthreads();
  d[(size_t)(c0 + ty) * R + (r0 + tx)] = __float2bfloat16(tile[tx][ty]);
}

// ---------------------------------------------------------------------------
extern "C" void kernel_launch(void* const* d_in, const int* in_sizes, int n_in,
                              void* d_out, int out_size, void* d_ws, size_t ws_size,
                              hipStream_t stream)
{
  const int*   a_seq     = (const int*)  d_in[0];
  const int*   b_seq     = (const int*)  d_in[1];
  const float* bit_emb   = (const float*)d_in[2];
  const float* start     = (const float*)d_in[3];
  const float* ln1_g     = (const float*)d_in[4];
  const float* ln1_b     = (const float*)d_in[5];
  const float* qkv_w     = (const float*)d_in[6];
  const float* qkv_b     = (const float*)d_in[7];
  const float* out_w     = (const float*)d_in[8];
  const float* out_b     = (const float*)d_in[9];
  const float* ln2_g     = (const float*)d_in[10];
  const float* ln2_b     = (const float*)d_in[11];
  const float* ff1_w     = (const float*)d_in[12];
  const float* ff1_b     = (const float*)d_in[13];
  const float* ff2_w     = (const float*)d_in[14];
  const float* ff2_b     = (const float*)d_in[15];
  const float* head_w    = (const float*)d_in[16];
  const float* head_b    = (const float*)d_in[17];
  float* out = (float*)d_out;

  // workspace layout
  char* ws = (char*)d_ws;
  float*  XA    = (float*) ws; ws += (size_t)B_ * D_ * 4;              // 8 MB
  float*  XB    = (float*) ws; ws += (size_t)B_ * D_ * 4;              // 8 MB
  bf16_t* Y     = (bf16_t*)ws; ws += (size_t)B_ * D_ * 2;              // 4 MB
  bf16_t* U     = (bf16_t*)ws; ws += (size_t)B_ * 4 * D_ * 2;          // 16 MB
  bf16_t* WCT   = (bf16_t*)ws; ws += (size_t)DEPTH_ * D_ * D_ * 2;     // 2 MB
  bf16_t* FF1T  = (bf16_t*)ws; ws += (size_t)DEPTH_ * D_ * 4 * D_ * 2; // 8 MB
  bf16_t* FF2T  = (bf16_t*)ws; ws += (size_t)DEPTH_ * 4 * D_ * D_ * 2; // 8 MB
  float*  BC    = (float*) ws; ws += (size_t)DEPTH_ * D_ * 4;          // 8 KB
  float*  WCTMP = (float*) ws; ws += (size_t)DEPTH_ * D_ * D_ * 4;     // 4 MB
  bf16_t* PSPL  = (bf16_t*)ws; ws += (size_t)SPLITZ * B_ * D_ * 2;     // 16 MB g3 split-K partials
  bf16_t* P1    = (bf16_t*)ws; ws += (size_t)B_ * D_ * 2;              // 4 MB g1 partial

  // ---- weight prep (per launch, identical every call) ----
  prep_wc<<<dim3(2, 512, 4), 256, 0, stream>>>(qkv_w, out_w, WCTMP);
  prep_bc<<<4, 512, 0, stream>>>(qkv_b, out_w, out_b, BC);
  transpose_conv<<<dim3(16, 16, 4),  dim3(32, 32), 0, stream>>>(WCTMP, WCT, 512, 512);
  transpose_conv<<<dim3(64, 16, 4),  dim3(32, 32), 0, stream>>>(ff1_w, FF1T, 512, 2048);
  transpose_conv<<<dim3(16, 64, 4),  dim3(32, 32), 0, stream>>>(ff2_w, FF2T, 2048, 512);

  // ---- recurrent steps ----
  // X ping-pong: addln XB->XA (l=0 residual base XA, ln_sum1 in-place),
  // lnfold l=1: XA->XB, l=2: XB->XA, l=3: XA->XB. Step ends on XB with
  // pending PSPL partials (folded by next addln / final head).
  for (int t = 0; t < S_; ++t) {
    if (t == 0)
      addln_gemm<<<dim3(B_ / 32, 4), 256, 0, stream>>>(
          a_seq, b_seq, bit_emb, start, 0, nullptr, XA,
          ln1_g, ln1_b, WCT, BC, P1, t, head_w, head_b, nullptr);
    else
      addln_gemm<<<dim3(B_ / 32, 4), 256, 0, stream>>>(
          a_seq, b_seq, bit_emb, XB, D_, PSPL, XA,
          ln1_g, ln1_b, WCT, BC, P1, t, head_w, head_b, out);
    float* cur = XA;
    float* alt = XB;
    for (int l = 0; l < DEPTH_; ++l) {
      if (l > 0) {
        // x = cur + fold(PSPL) -> alt ; y = LN1[l](x) ; P1 = y@Wc[l]+bc[l]
        lnfold_gemm<<<dim3(B_ / 32, 4), 256, 0, stream>>>(
            cur, PSPL, alt,
            ln1_g + (size_t)l * D_, ln1_b + (size_t)l * D_,
            WCT + (size_t)l * D_ * D_, BC + (size_t)l * D_, P1);
        float* tmp = cur; cur = alt; alt = tmp;
      }
      // x += P1 (in-place on cur) ; y = LN2[l](x)
      ln_sum1_kernel<<<B_ / 4, 256, 0, stream>>>(cur, P1,
                                                 ln2_g + (size_t)l * D_,
                                                 ln2_b + (size_t)l * D_, Y);
      // u = relu(y @ ff1[l] + b1)  (128x128, 8-wave dbuf prefetch)
      gemm_bf16<128, 128, 1, 1><<<dim3(32, 16), 512, 0, stream>>>(
          Y, FF1T + (size_t)l * D_ * 4 * D_, ff1_b + (size_t)l * 4 * D_, U,
          B_, 4 * D_, D_);
      // PSPL[z] = bf16(u @ ff2[l] (+b2 in z=0))  (128x128, split-K=4,
      //           8-wave dbuf prefetch, grid (32,4,4)=512 blocks)
      gemm_bf16<128, 128, 2, SPLITZ><<<dim3(32, 4, SPLITZ), 512, 0, stream>>>(
          U, FF2T + (size_t)l * 4 * D_ * D_, ff2_b + (size_t)l * D_, PSPL,
          B_, D_, 4 * D_);
      // partials folded by next lnfold / addln / head
    }
    // invariant: cur == XB here (addln wrote XA; 3 lnfold swaps -> XB)
  }
  head_kernel<<<B_ / 4, 256, 0, stream>>>(XB, PSPL, head_w, head_b, out, S_ - 1);
}

// Round 9
// 12891.223 us; speedup vs baseline: 1.1850x; 1.1850x over previous
//
#include <hip/hip_runtime.h>
#include <hip/hip_bf16.h>
#include <stdint.h>
#include <stddef.h>

// Problem constants
#define B_ 4096
#define S_ 64
#define D_ 512
#define DEPTH_ 4

// ---------------------------------------------------------------------------
// R19 design = R17 (best known, 14157us; R18's 8-wave reverted) + one delta:
//  * T2 XOR-swizzle on gemm_bf16's LDS tiles. R17's frag reads were a
//    16-way bank conflict (row stride 128B -> lanes 0-15 same bank window).
//    Per rule #21 (global_load_lds writes linearly): LDS dest stays linear,
//    the per-lane GLOBAL source col is pre-swizzled
//    (src_col = ((lane&7)^(lane>>3))*8 => LDS[r][b] = A[r][b ^ ((r&7)<<4)]),
//    and the ds_read applies the matching XOR (o ^ ((lane&7)<<3)).
//    Banks: 16-lane groups now tile all 32 banks at 2-way (free, m136).
//    Values bit-identical -> absmax unchanged. T2 regime gate: R17's
//    counted-vmcnt hid the stage stall, so the LDS read is now critical —
//    the quadrant where swizzle pays (m201/m252 mechanism).
//  * R18's 8-wave gemm REVERTED (+1.1ms: halved compute phase per wave +
//    doubled barrier cohort). 4 waves / 256 thr locked.
//  * Locked per R10-R17: dbuf counted-vmcnt prefetch (STAGE next ->
//    vmcnt(8) -> raw barrier -> MFMA -> raw barrier), BK=64,
//    global_load_lds w=16, small-GEMM direct-B + swizzled sY (R14),
//    split-K=4 g3 bf16 partials, X ping-pong, grids >=512 blocks,
//    no cross-block sync, no XCD swizzle.
//  * Failure modes mapped: R12 (TM<128 big GEMM), R15 (1 wave/SIMD),
//    R16 (direct-global big GEMM), R18 (8-wave lockstep).
// ---------------------------------------------------------------------------

typedef __attribute__((ext_vector_type(8))) __bf16 bf16x8;
typedef __attribute__((ext_vector_type(4))) float f32x4;
typedef __hip_bfloat16 bf16_t;

constexpr int SPLITZ = 4;   // g3 split-K partials

__device__ __forceinline__ void async_copy16(const void* g, void* lds) {
  __builtin_amdgcn_global_load_lds(
      (const __attribute__((address_space(1))) void*)g,
      (__attribute__((address_space(3))) void*)lds, 16, 0, 0);
}

__device__ __forceinline__ float bf2f(bf16_t h) { return __bfloat162float(h); }

// fold bf16 partial row-chunk into v[8]
__device__ __forceinline__ void fold_p(float v[8], const bf16_t* pz)
{
  alignas(16) bf16_t t[8];
  *(uint4*)t = *(const uint4*)pz;
#pragma unroll
  for (int i = 0; i < 8; ++i) v[i] += bf2f(t[i]);
}

// LayerNorm row math shared by the storers
__device__ __forceinline__ void ln_vals(const float v[8],
                                        const float* __restrict__ gamma,
                                        const float* __restrict__ beta,
                                        int lane, bf16_t o8[8])
{
  float s = 0.f, ss = 0.f;
#pragma unroll
  for (int i = 0; i < 8; ++i) { s += v[i]; ss += v[i] * v[i]; }
#pragma unroll
  for (int o = 32; o; o >>= 1) { s += __shfl_xor(s, o); ss += __shfl_xor(ss, o); }
  const float m   = s * (1.f / D_);
  const float inv = rsqrtf(ss * (1.f / D_) - m * m + 1e-5f);
  const int c0 = lane * 8;
  float g[8], b[8];
  *(float4*)&g[0] = *(const float4*)&gamma[c0];
  *(float4*)&g[4] = *(const float4*)&gamma[c0 + 4];
  *(float4*)&b[0] = *(const float4*)&beta[c0];
  *(float4*)&b[4] = *(const float4*)&beta[c0 + 4];
#pragma unroll
  for (int i = 0; i < 8; ++i)
    o8[i] = __float2bfloat16((v[i] - m) * inv * g[i] + b[i]);
}

// LN + plain row store (global Y rows)
__device__ __forceinline__ void ln_store(const float v[8],
                                         const float* __restrict__ gamma,
                                         const float* __restrict__ beta,
                                         bf16_t* yrow, int lane)
{
  alignas(16) bf16_t o8[8];
  ln_vals(v, gamma, beta, lane, o8);
  *(uint4*)&yrow[lane * 8] = *(const uint4*)o8;
}

// LN + XOR-swizzled LDS row store: elem ^= (row&7)<<3 (bank-spread for the
// stride-1024B ds_read_b128 in the K-loop; bijective within the row)
__device__ __forceinline__ void ln_store_swz(const float v[8],
                                             const float* __restrict__ gamma,
                                             const float* __restrict__ beta,
                                             bf16_t* srow, int row, int lane)
{
  alignas(16) bf16_t o8[8];
  ln_vals(v, gamma, beta, lane, o8);
  const int c0s = (lane * 8) ^ ((row & 7) << 3);
  *(uint4*)&srow[c0s] = *(const uint4*)o8;
}

// ---------------------------------------------------------------------------
// GEMM with 2-phase dbuf prefetch + T2-swizzled LDS: C = A @ Bt^T (+bias).
//   EPI 1: O[row*N+col]  = bf16(relu(acc+b))   (SPLITK==1)
//   EPI 2: O[z*M*N + row*N+col] = bf16(acc (+bias if z==0))
// Per-iter: STAGE(next tile) -> counted vmcnt(8) -> raw barrier ->
//           ds_read+MFMA -> raw barrier.
// LDS layout: LDS[r][b] = A[r][b ^ ((r&7)<<4 bytes)] via pre-swizzled
// global source; ds_read applies matching XOR.
// ---------------------------------------------------------------------------
template<int TM, int TN, int EPI, int SPLITK>
__launch_bounds__(256)
__global__ void gemm_bf16(const bf16_t* __restrict__ A,
                          const bf16_t* __restrict__ Bt,
                          const float* __restrict__ bias,
                          bf16_t* __restrict__ O,
                          int M, int N, int K)
{
  constexpr int BK  = 64;
  constexpr int WM  = TM / 2, WN = TN / 2;
  constexpr int NMI = WM / 16, NNI = WN / 16;
  constexpr int CA  = TM / 8, CB = TN / 8;   // 1KB chunks (8 rows of 128B)
  constexpr int BUF = (TM + TN) * BK;        // elems per stage buffer
  static_assert((CA + CB) / 4 == 8, "vmcnt(8) assumes 8 loads/wave/tile");
  static_assert(TM * TN <= BUF, "C tile must fit in one staging buffer");

  __shared__ __align__(16) bf16_t smem[2 * BUF];   // 64KB (2 blocks/CU cap)

  const int tid  = threadIdx.x;
  const int lane = tid & 63;
  const int wave = tid >> 6;
  const int wm   = wave & 1;
  const int wn   = wave >> 1;
  const int m0   = blockIdx.x * TM;
  const int n0   = blockIdx.y * TN;
  const int KS   = K / SPLITK;
  const int kbeg = blockIdx.z * KS;
  const int NI   = KS / BK;

  const int lr  = lane >> 3;                          // row within chunk
  const int lcs = (((lane & 7) ^ (lane >> 3)) << 3);  // pre-swizzled src col
  const int xo  = (lane & 7) << 3;                    // frag-read XOR (elems)

  f32x4 acc[NMI][NNI];
#pragma unroll
  for (int mi = 0; mi < NMI; ++mi)
#pragma unroll
    for (int ni = 0; ni < NNI; ++ni)
      acc[mi][ni] = (f32x4){0.f, 0.f, 0.f, 0.f};

  // stage one BK-tile into buffer b (8 global_load_lds per wave).
  // LDS dest linear; global source col pre-swizzled (rule #21).
  auto STAGE = [&](int k0, int b) {
    bf16_t* sA = smem + b * BUF;
    bf16_t* sB = sA + TM * BK;
#pragma unroll
    for (int c = wave; c < CA; c += 4)
      async_copy16(A + (size_t)(m0 + c * 8 + lr) * K + (k0 + lcs),
                   (char*)sA + c * 1024);
#pragma unroll
    for (int c = wave; c < CB; c += 4)
      async_copy16(Bt + (size_t)(n0 + c * 8 + lr) * K + (k0 + lcs),
                   (char*)sB + c * 1024);
  };

  STAGE(kbeg, 0);   // prologue: tile 0 in flight

  for (int i = 0; i < NI; ++i) {
    const int cur = i & 1;
    if (i + 1 < NI) {
      STAGE(kbeg + (i + 1) * BK, cur ^ 1);           // prefetch next tile
      asm volatile("s_waitcnt vmcnt(8)" ::: "memory"); // wait tile i only
    } else {
      asm volatile("s_waitcnt vmcnt(0)" ::: "memory");
    }
    __builtin_amdgcn_s_barrier();          // raw: no implicit vmcnt(0) drain
    __builtin_amdgcn_sched_barrier(0);

    const bf16_t* sA = smem + cur * BUF;
    const bf16_t* sB = sA + TM * BK;
#pragma unroll
    for (int kk = 0; kk < BK; kk += 32) {
      const int ko = (kk + (lane >> 4) * 8) ^ xo;   // swizzled frag offset
      bf16x8 af[NMI], bfv[NNI];
#pragma unroll
      for (int mi = 0; mi < NMI; ++mi)
        af[mi] = *(const bf16x8*)&sA[(wm * WM + mi * 16 + (lane & 15)) * BK + ko];
#pragma unroll
      for (int ni = 0; ni < NNI; ++ni)
        bfv[ni] = *(const bf16x8*)&sB[(wn * WN + ni * 16 + (lane & 15)) * BK + ko];
#pragma unroll
      for (int mi = 0; mi < NMI; ++mi)
#pragma unroll
        for (int ni = 0; ni < NNI; ++ni)
          acc[mi][ni] = __builtin_amdgcn_mfma_f32_16x16x32_bf16(af[mi], bfv[ni], acc[mi][ni], 0, 0, 0);
    }
    // each wave's ds_reads have returned (lgkmcnt before MFMA) before here
    __builtin_amdgcn_sched_barrier(0);
    __builtin_amdgcn_s_barrier();          // protect buf before next STAGE
  }

  // Coalesced epilogue: round into LDS (reuse staging buffer), then
  // row-major uint4 stores. C/D layout (m89/m91): col=lane&15,
  // row=(lane>>4)*4 + r.
  bf16_t* sC = smem;
#pragma unroll
  for (int mi = 0; mi < NMI; ++mi) {
#pragma unroll
    for (int ni = 0; ni < NNI; ++ni) {
      const int col  = wn * WN + ni * 16 + (lane & 15);
      const int row0 = wm * WM + mi * 16 + ((lane >> 4) << 2);
      const float bv = (SPLITK == 1 || blockIdx.z == 0) ? bias[n0 + col] : 0.f;
#pragma unroll
      for (int r = 0; r < 4; ++r) {
        float v = acc[mi][ni][r] + bv;
        if constexpr (EPI == 1) v = v > 0.f ? v : 0.f;
        sC[(row0 + r) * TN + col] = __float2bfloat16(v);
      }
    }
  }
  __syncthreads();
  bf16_t* Ob = O + (EPI == 2 ? (size_t)blockIdx.z * M * N : (size_t)0);
#pragma unroll
  for (int p = 0; p < (TM * TN) / 2048; ++p) {
    const int chunk = p * 256 + tid;
    const int rr = chunk / (TN / 8);
    const int cc = (chunk % (TN / 8)) * 8;
    *(uint4*)&Ob[(size_t)(m0 + rr) * N + n0 + cc] = *(const uint4*)&sC[rr * TN + cc];
  }
}

// x = X + P1 (bf16 partial); write X; y = LN(x). 4 rows/block.
__global__ void ln_sum1_kernel(float* __restrict__ X,
                               const bf16_t* __restrict__ P,
                               const float* __restrict__ gamma,
                               const float* __restrict__ beta,
                               bf16_t* __restrict__ Y)
{
  const int row  = blockIdx.x * 4 + (threadIdx.x >> 6);
  const int lane = threadIdx.x & 63;
  const int c0 = lane * 8;
  float* xr = X + (size_t)row * D_;
  float v[8];
  *(float4*)&v[0] = *(const float4*)&xr[c0];
  *(float4*)&v[4] = *(const float4*)&xr[c0 + 4];
  fold_p(v, P + (size_t)row * D_ + c0);
  *(float4*)&xr[c0]     = *(const float4*)&v[0];
  *(float4*)&xr[c0 + 4] = *(const float4*)&v[4];
  ln_store(v, gamma, beta, Y + (size_t)row * D_, lane);
}

// ---------------------------------------------------------------------------
// Barrier-free K-loop for the small D x D GEMM (shared by lnfold/addln):
// A = swizzled sY (LDS, written once), B = direct global (L2-hot Wc panel).
// ---------------------------------------------------------------------------
__device__ __forceinline__ void small_gemm_loop(const bf16_t* __restrict__ sY,
                                                const bf16_t* __restrict__ Bt,
                                                int n0, int wave, int lane,
                                                f32x4 acc[2][2])
{
  const bf16_t* b0 = Bt + (size_t)(n0 + wave * 32 + (lane & 15)) * D_ + (lane >> 4) * 8;
  const bf16_t* b1 = b0 + (size_t)16 * D_;
  const int r0 = (lane & 15);
  const int r1 = 16 + (lane & 15);
  const int x0 = (r0 & 7) << 3;          // swizzle XOR for rows 0-15
  const int ka = (lane >> 4) * 8;
#pragma unroll
  for (int k0 = 0; k0 < D_; k0 += 32) {
    bf16x8 af0, af1, bv0, bv1;
    bv0 = *(const bf16x8*)&b0[k0];
    bv1 = *(const bf16x8*)&b1[k0];
    af0 = *(const bf16x8*)&sY[r0 * D_ + ((k0 + ka) ^ x0)];
    af1 = *(const bf16x8*)&sY[r1 * D_ + ((k0 + ka) ^ x0)];  // (r1&7)==(r0&7)
    acc[0][0] = __builtin_amdgcn_mfma_f32_16x16x32_bf16(af0, bv0, acc[0][0], 0, 0, 0);
    acc[0][1] = __builtin_amdgcn_mfma_f32_16x16x32_bf16(af0, bv1, acc[0][1], 0, 0, 0);
    acc[1][0] = __builtin_amdgcn_mfma_f32_16x16x32_bf16(af1, bv0, acc[1][0], 0, 0, 0);
    acc[1][1] = __builtin_amdgcn_mfma_f32_16x16x32_bf16(af1, bv1, acc[1][1], 0, 0, 0);
  }
}

// shared coalesced epilogue through sC (=sY reused) for the small GEMMs
__device__ __forceinline__ void small_gemm_epi(bf16_t* sC, bf16_t* __restrict__ O,
                                               const float* __restrict__ bias,
                                               const f32x4 acc[2][2],
                                               int m0, int n0, int wave, int lane,
                                               int tid)
{
  constexpr int TM = 32, TN = 128;
#pragma unroll
  for (int mi = 0; mi < 2; ++mi) {
#pragma unroll
    for (int ni = 0; ni < 2; ++ni) {
      const int col  = wave * 32 + ni * 16 + (lane & 15);
      const int row0 = mi * 16 + ((lane >> 4) << 2);
      const float bv = bias[n0 + col];
#pragma unroll
      for (int r = 0; r < 4; ++r)
        sC[(row0 + r) * TN + col] = __float2bfloat16(acc[mi][ni][r] + bv);
    }
  }
  __syncthreads();
#pragma unroll
  for (int p = 0; p < (TM * TN) / 2048; ++p) {   // 2 passes
    const int chunk = p * 256 + tid;
    const int rr = chunk / (TN / 8);
    const int cc = (chunk % (TN / 8)) * 8;
    *(uint4*)&O[(size_t)(m0 + rr) * D_ + n0 + cc] = *(const uint4*)&sC[rr * TN + cc];
  }
}

// ---------------------------------------------------------------------------
// Fused [x = Xin + sum_{z<4} PSPL; LN1; P1 = y@Wc + bc], layers 1..3.
// TM=32 rows, TN=128 cols; grid (B/32, 4) = 512 blocks, 256 thr.
// LDS: sY 32KB only. Two barriers total (post-prologue, pre-epilogue).
// blockIdx.y==0 writes Xout (ping-pong buffer, no race with Xin reads).
// ---------------------------------------------------------------------------
__launch_bounds__(256)
__global__ void lnfold_gemm(const float* __restrict__ Xin,
                            const bf16_t* __restrict__ P,
                            float* __restrict__ Xout,
                            const float* __restrict__ gamma,
                            const float* __restrict__ beta,
                            const bf16_t* __restrict__ Bt,   // WCT layer slice
                            const float* __restrict__ bias,  // BC layer slice
                            bf16_t* __restrict__ O)          // P1
{
  constexpr int TM = 32;
  __shared__ __align__(16) bf16_t sY[TM * D_];   // 32KB

  const int tid  = threadIdx.x;
  const int lane = tid & 63;
  const int wave = tid >> 6;
  const int m0   = blockIdx.x * TM;
  const int n0   = blockIdx.y * 128;
  const int c0   = lane * 8;

  // ---- prologue: fold partials + LN (swizzled store), 8 rows per wave ----
#pragma unroll
  for (int i = 0; i < 8; ++i) {
    const int row  = wave * 8 + i;
    const int grow = m0 + row;
    const float* xr = Xin + (size_t)grow * D_ + c0;
    float v[8];
    *(float4*)&v[0] = *(const float4*)&xr[0];
    *(float4*)&v[4] = *(const float4*)&xr[4];
#pragma unroll
    for (int z = 0; z < SPLITZ; ++z)
      fold_p(v, P + (size_t)z * B_ * D_ + (size_t)grow * D_ + c0);
    if (blockIdx.y == 0) {
      float* xo = Xout + (size_t)grow * D_ + c0;
      *(float4*)&xo[0] = *(const float4*)&v[0];
      *(float4*)&xo[4] = *(const float4*)&v[4];
    }
    ln_store_swz(v, gamma, beta, &sY[row * D_], row, lane);
  }
  __syncthreads();   // sY visible to all waves

  f32x4 acc[2][2];
#pragma unroll
  for (int mi = 0; mi < 2; ++mi)
#pragma unroll
    for (int ni = 0; ni < 2; ++ni)
      acc[mi][ni] = (f32x4){0.f, 0.f, 0.f, 0.f};

  small_gemm_loop(sY, Bt, n0, wave, lane, acc);

  __syncthreads();   // all sY reads done before reuse as sC
  small_gemm_epi(sY, O, bias, acc, m0, n0, wave, lane, tid);
}

// ---------------------------------------------------------------------------
// Fused step boundary + g1 (layer 0):
//  h = hsrc (+ fold PSPL if P); head(t-1) from h (if out, blockIdx.y==0);
//  x = emb_a + emb_b + h -> Xout (y==0); y = LN1_0(x) -> sY (swizzled);
//  P1 = y @ Wc0 + bc0.  Same geometry as lnfold_gemm.
// ---------------------------------------------------------------------------
__launch_bounds__(256)
__global__ void addln_gemm(const int* __restrict__ a_seq,
                           const int* __restrict__ b_seq,
                           const float* __restrict__ bit_emb,
                           const float* __restrict__ hsrc, int hstride,
                           const bf16_t* __restrict__ P,
                           float* __restrict__ Xout,
                           const float* __restrict__ gamma,
                           const float* __restrict__ beta,
                           const bf16_t* __restrict__ Bt,   // WCT layer 0
                           const float* __restrict__ bias,  // BC layer 0
                           bf16_t* __restrict__ O,          // P1
                           int t,
                           const float* __restrict__ hw,
                           const float* __restrict__ hb,
                           float* __restrict__ out)
{
  constexpr int TM = 32;
  __shared__ __align__(16) bf16_t sY[TM * D_];   // 32KB

  const int tid  = threadIdx.x;
  const int lane = tid & 63;
  const int wave = tid >> 6;
  const int m0   = blockIdx.x * TM;
  const int n0   = blockIdx.y * 128;
  const int c0   = lane * 8;

  const bool do_head = (out != nullptr) && (blockIdx.y == 0);
  float w[16];
  if (do_head) {
#pragma unroll
    for (int i = 0; i < 4; ++i)
      *(float4*)&w[i * 4] = *(const float4*)&hw[lane * 16 + i * 4];
  }

#pragma unroll
  for (int i = 0; i < 8; ++i) {
    const int row  = wave * 8 + i;
    const int grow = m0 + row;
    const int ai = a_seq[grow * S_ + t];
    const int bi = b_seq[grow * S_ + t];
    const float* pr = hsrc + (size_t)grow * hstride + c0;
    float p[8];
    *(float4*)&p[0] = *(const float4*)&pr[0];
    *(float4*)&p[4] = *(const float4*)&pr[4];
    if (P != nullptr) {
#pragma unroll
      for (int z = 0; z < SPLITZ; ++z)
        fold_p(p, P + (size_t)z * B_ * D_ + (size_t)grow * D_ + c0);
    }
    if (do_head) {
      float s0 = 0.f, s1 = 0.f;
#pragma unroll
      for (int j = 0; j < 8; ++j) { s0 += p[j] * w[2 * j]; s1 += p[j] * w[2 * j + 1]; }
#pragma unroll
      for (int o = 32; o; o >>= 1) { s0 += __shfl_xor(s0, o); s1 += __shfl_xor(s1, o); }
      if (lane == 0) {
        float* po = out + (size_t)grow * (S_ * 2) + (t - 1) * 2;
        po[0] = s0 + hb[0];
        po[1] = s1 + hb[1];
      }
    }
    float ea[8], eb[8], v[8];
    *(float4*)&ea[0] = *(const float4*)&bit_emb[ai * D_ + c0];
    *(float4*)&ea[4] = *(const float4*)&bit_emb[ai * D_ + c0 + 4];
    *(float4*)&eb[0] = *(const float4*)&bit_emb[bi * D_ + c0];
    *(float4*)&eb[4] = *(const float4*)&bit_emb[bi * D_ + c0 + 4];
#pragma unroll
    for (int j = 0; j < 8; ++j) v[j] = ea[j] + eb[j] + p[j];
    if (blockIdx.y == 0) {
      float* xo = Xout + (size_t)grow * D_ + c0;
      *(float4*)&xo[0] = *(const float4*)&v[0];
      *(float4*)&xo[4] = *(const float4*)&v[4];
    }
    ln_store_swz(v, gamma, beta, &sY[row * D_], row, lane);
  }
  __syncthreads();   // sY visible

  f32x4 acc[2][2];
#pragma unroll
  for (int mi = 0; mi < 2; ++mi)
#pragma unroll
    for (int ni = 0; ni < 2; ++ni)
      acc[mi][ni] = (f32x4){0.f, 0.f, 0.f, 0.f};

  small_gemm_loop(sY, Bt, n0, wave, lane, acc);

  __syncthreads();
  small_gemm_epi(sY, O, bias, acc, m0, n0, wave, lane, tid);
}

// Final head: h = X + P0..P3; logits[row, S-1, :] = h @ head_w + head_b.
__global__ void head_kernel(const float* __restrict__ X,
                            const bf16_t* __restrict__ P,
                            const float* __restrict__ hw,
                            const float* __restrict__ hb,
                            float* __restrict__ out, int t)
{
  const int row  = blockIdx.x * 4 + (threadIdx.x >> 6);
  const int lane = threadIdx.x & 63;
  const float* xr = X + (size_t)row * D_;
  const int c0 = lane * 8;
  float v[8];
  *(float4*)&v[0] = *(const float4*)&xr[c0];
  *(float4*)&v[4] = *(const float4*)&xr[c0 + 4];
#pragma unroll
  for (int z = 0; z < SPLITZ; ++z)
    fold_p(v, P + (size_t)z * B_ * D_ + (size_t)row * D_ + c0);
  float w[16];
#pragma unroll
  for (int i = 0; i < 4; ++i)
    *(float4*)&w[i * 4] = *(const float4*)&hw[lane * 16 + i * 4];
  float s0 = 0.f, s1 = 0.f;
#pragma unroll
  for (int i = 0; i < 8; ++i) { s0 += v[i] * w[2 * i]; s1 += v[i] * w[2 * i + 1]; }
#pragma unroll
  for (int o = 32; o; o >>= 1) { s0 += __shfl_xor(s0, o); s1 += __shfl_xor(s1, o); }
  if (lane == 0) {
    float* po = out + (size_t)row * (S_ * 2) + t * 2;
    po[0] = s0 + hb[0];
    po[1] = s1 + hb[1];
  }
}

// ---------------------------------------------------------------------------
// Prep kernels (run every launch; graph-safe)
// ---------------------------------------------------------------------------
__global__ void prep_wc(const float* __restrict__ qkv_w,
                        const float* __restrict__ out_w,
                        float* __restrict__ wc)
{
  const int n = blockIdx.x * 256 + threadIdx.x;
  const int k = blockIdx.y;
  const int l = blockIdx.z;
  const float* qrow = qkv_w + ((size_t)l * D_ + k) * (3 * D_) + 2 * D_;
  const float* ow   = out_w + (size_t)l * D_ * D_;
  float acc = 0.f;
  for (int j = 0; j < D_; ++j) acc += qrow[j] * ow[(size_t)j * D_ + n];
  wc[((size_t)l * D_ + k) * D_ + n] = acc;
}

__global__ void prep_bc(const float* __restrict__ qkv_b,
                        const float* __restrict__ out_w,
                        const float* __restrict__ out_b,
                        float* __restrict__ bc)
{
  const int l = blockIdx.x;
  const int n = threadIdx.x;
  const float* qb = qkv_b + (size_t)l * (3 * D_) + 2 * D_;
  const float* ow = out_w + (size_t)l * D_ * D_;
  float acc = out_b[(size_t)l * D_ + n];
  for (int j = 0; j < D_; ++j) acc += qb[j] * ow[(size_t)j * D_ + n];
  bc[(size_t)l * D_ + n] = acc;
}

// dst(C,R) bf16 = transpose(src(R,C) fp32), per-layer via blockIdx.z
__global__ void transpose_conv(const float* __restrict__ src,
                               bf16_t* __restrict__ dst, int R, int C)
{
  __shared__ float tile[32][33];
  const int l = blockIdx.z;
  const float* s = src + (size_t)l * R * C;
  bf16_t* d = dst + (size_t)l * R * C;
  const int c0 = blockIdx.x * 32, r0 = blockIdx.y * 32;
  const int tx = threadIdx.x, ty = threadIdx.y;
  tile[ty][tx] = s[(size_t)(r0 + ty) * C + (c0 + tx)];
  __syncthreads();
  d[(size_t)(c0 + ty) * R + (r0 + tx)] = __float2bfloat16(tile[tx][ty]);
}

// ---------------------------------------------------------------------------
extern "C" void kernel_launch(void* const* d_in, const int* in_sizes, int n_in,
                              void* d_out, int out_size, void* d_ws, size_t ws_size,
                              hipStream_t stream)
{
  const int*   a_seq     = (const int*)  d_in[0];
  const int*   b_seq     = (const int*)  d_in[1];
  const float* bit_emb   = (const float*)d_in[2];
  const float* start     = (const float*)d_in[3];
  const float* ln1_g     = (const float*)d_in[4];
  const float* ln1_b     = (const float*)d_in[5];
  const float* qkv_w     = (const float*)d_in[6];
  const float* qkv_b     = (const float*)d_in[7];
  const float* out_w     = (const float*)d_in[8];
  const float* out_b     = (const float*)d_in[9];
  const float* ln2_g     = (const float*)d_in[10];
  const float* ln2_b     = (const float*)d_in[11];
  const float* ff1_w     = (const float*)d_in[12];
  const float* ff1_b     = (const float*)d_in[13];
  const float* ff2_w     = (const float*)d_in[14];
  const float* ff2_b     = (const float*)d_in[15];
  const float* head_w    = (const float*)d_in[16];
  const float* head_b    = (const float*)d_in[17];
  float* out = (float*)d_out;

  // workspace layout
  char* ws = (char*)d_ws;
  float*  XA    = (float*) ws; ws += (size_t)B_ * D_ * 4;              // 8 MB
  float*  XB    = (float*) ws; ws += (size_t)B_ * D_ * 4;              // 8 MB
  bf16_t* Y     = (bf16_t*)ws; ws += (size_t)B_ * D_ * 2;              // 4 MB
  bf16_t* U     = (bf16_t*)ws; ws += (size_t)B_ * 4 * D_ * 2;          // 16 MB
  bf16_t* WCT   = (bf16_t*)ws; ws += (size_t)DEPTH_ * D_ * D_ * 2;     // 2 MB
  bf16_t* FF1T  = (bf16_t*)ws; ws += (size_t)DEPTH_ * D_ * 4 * D_ * 2; // 8 MB
  bf16_t* FF2T  = (bf16_t*)ws; ws += (size_t)DEPTH_ * 4 * D_ * D_ * 2; // 8 MB
  float*  BC    = (float*) ws; ws += (size_t)DEPTH_ * D_ * 4;          // 8 KB
  float*  WCTMP = (float*) ws; ws += (size_t)DEPTH_ * D_ * D_ * 4;     // 4 MB
  bf16_t* PSPL  = (bf16_t*)ws; ws += (size_t)SPLITZ * B_ * D_ * 2;     // 16 MB g3 split-K partials
  bf16_t* P1    = (bf16_t*)ws; ws += (size_t)B_ * D_ * 2;              // 4 MB g1 partial

  // ---- weight prep (per launch, identical every call) ----
  prep_wc<<<dim3(2, 512, 4), 256, 0, stream>>>(qkv_w, out_w, WCTMP);
  prep_bc<<<4, 512, 0, stream>>>(qkv_b, out_w, out_b, BC);
  transpose_conv<<<dim3(16, 16, 4),  dim3(32, 32), 0, stream>>>(WCTMP, WCT, 512, 512);
  transpose_conv<<<dim3(64, 16, 4),  dim3(32, 32), 0, stream>>>(ff1_w, FF1T, 512, 2048);
  transpose_conv<<<dim3(16, 64, 4),  dim3(32, 32), 0, stream>>>(ff2_w, FF2T, 2048, 512);

  // ---- recurrent steps ----
  // X ping-pong: addln XB->XA (l=0 residual base XA, ln_sum1 in-place),
  // lnfold l=1: XA->XB, l=2: XB->XA, l=3: XA->XB. Step ends on XB with
  // pending PSPL partials (folded by next addln / final head).
  for (int t = 0; t < S_; ++t) {
    if (t == 0)
      addln_gemm<<<dim3(B_ / 32, 4), 256, 0, stream>>>(
          a_seq, b_seq, bit_emb, start, 0, nullptr, XA,
          ln1_g, ln1_b, WCT, BC, P1, t, head_w, head_b, nullptr);
    else
      addln_gemm<<<dim3(B_ / 32, 4), 256, 0, stream>>>(
          a_seq, b_seq, bit_emb, XB, D_, PSPL, XA,
          ln1_g, ln1_b, WCT, BC, P1, t, head_w, head_b, out);
    float* cur = XA;
    float* alt = XB;
    for (int l = 0; l < DEPTH_; ++l) {
      if (l > 0) {
        // x = cur + fold(PSPL) -> alt ; y = LN1[l](x) ; P1 = y@Wc[l]+bc[l]
        lnfold_gemm<<<dim3(B_ / 32, 4), 256, 0, stream>>>(
            cur, PSPL, alt,
            ln1_g + (size_t)l * D_, ln1_b + (size_t)l * D_,
            WCT + (size_t)l * D_ * D_, BC + (size_t)l * D_, P1);
        float* tmp = cur; cur = alt; alt = tmp;
      }
      // x += P1 (in-place on cur) ; y = LN2[l](x)
      ln_sum1_kernel<<<B_ / 4, 256, 0, stream>>>(cur, P1,
                                                 ln2_g + (size_t)l * D_,
                                                 ln2_b + (size_t)l * D_, Y);
      // u = relu(y @ ff1[l] + b1)  (128x128, dbuf prefetch + T2 swizzle)
      gemm_bf16<128, 128, 1, 1><<<dim3(32, 16), 256, 0, stream>>>(
          Y, FF1T + (size_t)l * D_ * 4 * D_, ff1_b + (size_t)l * 4 * D_, U,
          B_, 4 * D_, D_);
      // PSPL[z] = bf16(u @ ff2[l] (+b2 in z=0))  (128x128, split-K=4,
      //           dbuf prefetch + T2 swizzle, grid (32,4,4)=512 blocks)
      gemm_bf16<128, 128, 2, SPLITZ><<<dim3(32, 4, SPLITZ), 256, 0, stream>>>(
          U, FF2T + (size_t)l * 4 * D_ * D_, ff2_b + (size_t)l * D_, PSPL,
          B_, D_, 4 * D_);
      // partials folded by next lnfold / addln / head
    }
    // invariant: cur == XB here (addln wrote XA; 3 lnfold swaps -> XB)
  }
  head_kernel<<<B_ / 4, 256, 0, stream>>>(XB, PSPL, head_w, head_b, out, S_ - 1);
}

// Round 10
// 12695.663 us; speedup vs baseline: 1.2033x; 1.0154x over previous
//
#include <hip/hip_runtime.h>
#include <hip/hip_bf16.h>
#include <stdint.h>
#include <stddef.h>

// Problem constants
#define B_ 4096
#define S_ 64
#define D_ 512
#define DEPTH_ 4

// ---------------------------------------------------------------------------
// R20 design = R19 (best known, 12891us) + one delta:
//  * T5 s_setprio(1) around the MFMA compute phase of gemm_bf16 and the
//    K-loop of small_gemm_loop. Mechanism: R17/R19's counted-vmcnt
//    structure gives co-resident blocks wave role diversity (one block's
//    waves MFMA while the other's stage); setprio biases the SIMD
//    scheduler toward the MFMA-issuing waves (T5 pays only with role
//    diversity — null on lockstep drain structures, m190).
//    Pure hint: no correctness/occupancy change, absmax unchanged.
//  * Locked per R10-R19: 2-phase dbuf counted-vmcnt prefetch + T2 LDS
//    XOR-swizzle in big GEMMs (R17+R19, -1.86ms combined), 4 waves/256thr
//    (R18 anti-lesson), BK=64, global_load_lds w=16, small-GEMM direct-B
//    + swizzled sY (R14), split-K=4 g3 bf16 partials, X ping-pong,
//    grids >=512 blocks, no cross-block sync, no XCD swizzle.
//  * Failure modes mapped: R12 (TM<128 big GEMM), R15 (1 wave/SIMD),
//    R16 (direct-global big GEMM), R18 (8-wave lockstep).
// ---------------------------------------------------------------------------

typedef __attribute__((ext_vector_type(8))) __bf16 bf16x8;
typedef __attribute__((ext_vector_type(4))) float f32x4;
typedef __hip_bfloat16 bf16_t;

constexpr int SPLITZ = 4;   // g3 split-K partials

__device__ __forceinline__ void async_copy16(const void* g, void* lds) {
  __builtin_amdgcn_global_load_lds(
      (const __attribute__((address_space(1))) void*)g,
      (__attribute__((address_space(3))) void*)lds, 16, 0, 0);
}

__device__ __forceinline__ float bf2f(bf16_t h) { return __bfloat162float(h); }

// fold bf16 partial row-chunk into v[8]
__device__ __forceinline__ void fold_p(float v[8], const bf16_t* pz)
{
  alignas(16) bf16_t t[8];
  *(uint4*)t = *(const uint4*)pz;
#pragma unroll
  for (int i = 0; i < 8; ++i) v[i] += bf2f(t[i]);
}

// LayerNorm row math shared by the storers
__device__ __forceinline__ void ln_vals(const float v[8],
                                        const float* __restrict__ gamma,
                                        const float* __restrict__ beta,
                                        int lane, bf16_t o8[8])
{
  float s = 0.f, ss = 0.f;
#pragma unroll
  for (int i = 0; i < 8; ++i) { s += v[i]; ss += v[i] * v[i]; }
#pragma unroll
  for (int o = 32; o; o >>= 1) { s += __shfl_xor(s, o); ss += __shfl_xor(ss, o); }
  const float m   = s * (1.f / D_);
  const float inv = rsqrtf(ss * (1.f / D_) - m * m + 1e-5f);
  const int c0 = lane * 8;
  float g[8], b[8];
  *(float4*)&g[0] = *(const float4*)&gamma[c0];
  *(float4*)&g[4] = *(const float4*)&gamma[c0 + 4];
  *(float4*)&b[0] = *(const float4*)&beta[c0];
  *(float4*)&b[4] = *(const float4*)&beta[c0 + 4];
#pragma unroll
  for (int i = 0; i < 8; ++i)
    o8[i] = __float2bfloat16((v[i] - m) * inv * g[i] + b[i]);
}

// LN + plain row store (global Y rows)
__device__ __forceinline__ void ln_store(const float v[8],
                                         const float* __restrict__ gamma,
                                         const float* __restrict__ beta,
                                         bf16_t* yrow, int lane)
{
  alignas(16) bf16_t o8[8];
  ln_vals(v, gamma, beta, lane, o8);
  *(uint4*)&yrow[lane * 8] = *(const uint4*)o8;
}

// LN + XOR-swizzled LDS row store: elem ^= (row&7)<<3 (bank-spread for the
// stride-1024B ds_read_b128 in the K-loop; bijective within the row)
__device__ __forceinline__ void ln_store_swz(const float v[8],
                                             const float* __restrict__ gamma,
                                             const float* __restrict__ beta,
                                             bf16_t* srow, int row, int lane)
{
  alignas(16) bf16_t o8[8];
  ln_vals(v, gamma, beta, lane, o8);
  const int c0s = (lane * 8) ^ ((row & 7) << 3);
  *(uint4*)&srow[c0s] = *(const uint4*)o8;
}

// ---------------------------------------------------------------------------
// GEMM with 2-phase dbuf prefetch + T2-swizzled LDS + T5 setprio:
//   C = A @ Bt^T (+bias).
//   EPI 1: O[row*N+col]  = bf16(relu(acc+b))   (SPLITK==1)
//   EPI 2: O[z*M*N + row*N+col] = bf16(acc (+bias if z==0))
// Per-iter: STAGE(next tile) -> counted vmcnt(8) -> raw barrier ->
//           setprio(1) ds_read+MFMA setprio(0) -> raw barrier.
// LDS layout: LDS[r][b] = A[r][b ^ ((r&7)<<4 bytes)] via pre-swizzled
// global source; ds_read applies matching XOR.
// ---------------------------------------------------------------------------
template<int TM, int TN, int EPI, int SPLITK>
__launch_bounds__(256)
__global__ void gemm_bf16(const bf16_t* __restrict__ A,
                          const bf16_t* __restrict__ Bt,
                          const float* __restrict__ bias,
                          bf16_t* __restrict__ O,
                          int M, int N, int K)
{
  constexpr int BK  = 64;
  constexpr int WM  = TM / 2, WN = TN / 2;
  constexpr int NMI = WM / 16, NNI = WN / 16;
  constexpr int CA  = TM / 8, CB = TN / 8;   // 1KB chunks (8 rows of 128B)
  constexpr int BUF = (TM + TN) * BK;        // elems per stage buffer
  static_assert((CA + CB) / 4 == 8, "vmcnt(8) assumes 8 loads/wave/tile");
  static_assert(TM * TN <= BUF, "C tile must fit in one staging buffer");

  __shared__ __align__(16) bf16_t smem[2 * BUF];   // 64KB (2 blocks/CU cap)

  const int tid  = threadIdx.x;
  const int lane = tid & 63;
  const int wave = tid >> 6;
  const int wm   = wave & 1;
  const int wn   = wave >> 1;
  const int m0   = blockIdx.x * TM;
  const int n0   = blockIdx.y * TN;
  const int KS   = K / SPLITK;
  const int kbeg = blockIdx.z * KS;
  const int NI   = KS / BK;

  const int lr  = lane >> 3;                          // row within chunk
  const int lcs = (((lane & 7) ^ (lane >> 3)) << 3);  // pre-swizzled src col
  const int xo  = (lane & 7) << 3;                    // frag-read XOR (elems)

  f32x4 acc[NMI][NNI];
#pragma unroll
  for (int mi = 0; mi < NMI; ++mi)
#pragma unroll
    for (int ni = 0; ni < NNI; ++ni)
      acc[mi][ni] = (f32x4){0.f, 0.f, 0.f, 0.f};

  // stage one BK-tile into buffer b (8 global_load_lds per wave).
  // LDS dest linear; global source col pre-swizzled (rule #21).
  auto STAGE = [&](int k0, int b) {
    bf16_t* sA = smem + b * BUF;
    bf16_t* sB = sA + TM * BK;
#pragma unroll
    for (int c = wave; c < CA; c += 4)
      async_copy16(A + (size_t)(m0 + c * 8 + lr) * K + (k0 + lcs),
                   (char*)sA + c * 1024);
#pragma unroll
    for (int c = wave; c < CB; c += 4)
      async_copy16(Bt + (size_t)(n0 + c * 8 + lr) * K + (k0 + lcs),
                   (char*)sB + c * 1024);
  };

  STAGE(kbeg, 0);   // prologue: tile 0 in flight

  for (int i = 0; i < NI; ++i) {
    const int cur = i & 1;
    if (i + 1 < NI) {
      STAGE(kbeg + (i + 1) * BK, cur ^ 1);           // prefetch next tile
      asm volatile("s_waitcnt vmcnt(8)" ::: "memory"); // wait tile i only
    } else {
      asm volatile("s_waitcnt vmcnt(0)" ::: "memory");
    }
    __builtin_amdgcn_s_barrier();          // raw: no implicit vmcnt(0) drain
    __builtin_amdgcn_sched_barrier(0);
    __builtin_amdgcn_s_setprio(1);         // T5: favor MFMA-phase waves

    const bf16_t* sA = smem + cur * BUF;
    const bf16_t* sB = sA + TM * BK;
#pragma unroll
    for (int kk = 0; kk < BK; kk += 32) {
      const int ko = (kk + (lane >> 4) * 8) ^ xo;   // swizzled frag offset
      bf16x8 af[NMI], bfv[NNI];
#pragma unroll
      for (int mi = 0; mi < NMI; ++mi)
        af[mi] = *(const bf16x8*)&sA[(wm * WM + mi * 16 + (lane & 15)) * BK + ko];
#pragma unroll
      for (int ni = 0; ni < NNI; ++ni)
        bfv[ni] = *(const bf16x8*)&sB[(wn * WN + ni * 16 + (lane & 15)) * BK + ko];
#pragma unroll
      for (int mi = 0; mi < NMI; ++mi)
#pragma unroll
        for (int ni = 0; ni < NNI; ++ni)
          acc[mi][ni] = __builtin_amdgcn_mfma_f32_16x16x32_bf16(af[mi], bfv[ni], acc[mi][ni], 0, 0, 0);
    }
    __builtin_amdgcn_s_setprio(0);
    // each wave's ds_reads have returned (lgkmcnt before MFMA) before here
    __builtin_amdgcn_sched_barrier(0);
    __builtin_amdgcn_s_barrier();          // protect buf before next STAGE
  }

  // Coalesced epilogue: round into LDS (reuse staging buffer), then
  // row-major uint4 stores. C/D layout (m89/m91): col=lane&15,
  // row=(lane>>4)*4 + r.
  bf16_t* sC = smem;
#pragma unroll
  for (int mi = 0; mi < NMI; ++mi) {
#pragma unroll
    for (int ni = 0; ni < NNI; ++ni) {
      const int col  = wn * WN + ni * 16 + (lane & 15);
      const int row0 = wm * WM + mi * 16 + ((lane >> 4) << 2);
      const float bv = (SPLITK == 1 || blockIdx.z == 0) ? bias[n0 + col] : 0.f;
#pragma unroll
      for (int r = 0; r < 4; ++r) {
        float v = acc[mi][ni][r] + bv;
        if constexpr (EPI == 1) v = v > 0.f ? v : 0.f;
        sC[(row0 + r) * TN + col] = __float2bfloat16(v);
      }
    }
  }
  __syncthreads();
  bf16_t* Ob = O + (EPI == 2 ? (size_t)blockIdx.z * M * N : (size_t)0);
#pragma unroll
  for (int p = 0; p < (TM * TN) / 2048; ++p) {
    const int chunk = p * 256 + tid;
    const int rr = chunk / (TN / 8);
    const int cc = (chunk % (TN / 8)) * 8;
    *(uint4*)&Ob[(size_t)(m0 + rr) * N + n0 + cc] = *(const uint4*)&sC[rr * TN + cc];
  }
}

// x = X + P1 (bf16 partial); write X; y = LN(x). 4 rows/block.
__global__ void ln_sum1_kernel(float* __restrict__ X,
                               const bf16_t* __restrict__ P,
                               const float* __restrict__ gamma,
                               const float* __restrict__ beta,
                               bf16_t* __restrict__ Y)
{
  const int row  = blockIdx.x * 4 + (threadIdx.x >> 6);
  const int lane = threadIdx.x & 63;
  const int c0 = lane * 8;
  float* xr = X + (size_t)row * D_;
  float v[8];
  *(float4*)&v[0] = *(const float4*)&xr[c0];
  *(float4*)&v[4] = *(const float4*)&xr[c0 + 4];
  fold_p(v, P + (size_t)row * D_ + c0);
  *(float4*)&xr[c0]     = *(const float4*)&v[0];
  *(float4*)&xr[c0 + 4] = *(const float4*)&v[4];
  ln_store(v, gamma, beta, Y + (size_t)row * D_, lane);
}

// ---------------------------------------------------------------------------
// Barrier-free K-loop for the small D x D GEMM (shared by lnfold/addln):
// A = swizzled sY (LDS, written once), B = direct global (L2-hot Wc panel).
// T5: whole loop wrapped in setprio(1) — favors K-loop waves over the
// co-resident blocks still in their VALU/load prologue.
// ---------------------------------------------------------------------------
__device__ __forceinline__ void small_gemm_loop(const bf16_t* __restrict__ sY,
                                                const bf16_t* __restrict__ Bt,
                                                int n0, int wave, int lane,
                                                f32x4 acc[2][2])
{
  const bf16_t* b0 = Bt + (size_t)(n0 + wave * 32 + (lane & 15)) * D_ + (lane >> 4) * 8;
  const bf16_t* b1 = b0 + (size_t)16 * D_;
  const int r0 = (lane & 15);
  const int r1 = 16 + (lane & 15);
  const int x0 = (r0 & 7) << 3;          // swizzle XOR for rows 0-15
  const int ka = (lane >> 4) * 8;
  __builtin_amdgcn_s_setprio(1);
#pragma unroll
  for (int k0 = 0; k0 < D_; k0 += 32) {
    bf16x8 af0, af1, bv0, bv1;
    bv0 = *(const bf16x8*)&b0[k0];
    bv1 = *(const bf16x8*)&b1[k0];
    af0 = *(const bf16x8*)&sY[r0 * D_ + ((k0 + ka) ^ x0)];
    af1 = *(const bf16x8*)&sY[r1 * D_ + ((k0 + ka) ^ x0)];  // (r1&7)==(r0&7)
    acc[0][0] = __builtin_amdgcn_mfma_f32_16x16x32_bf16(af0, bv0, acc[0][0], 0, 0, 0);
    acc[0][1] = __builtin_amdgcn_mfma_f32_16x16x32_bf16(af0, bv1, acc[0][1], 0, 0, 0);
    acc[1][0] = __builtin_amdgcn_mfma_f32_16x16x32_bf16(af1, bv0, acc[1][0], 0, 0, 0);
    acc[1][1] = __builtin_amdgcn_mfma_f32_16x16x32_bf16(af1, bv1, acc[1][1], 0, 0, 0);
  }
  __builtin_amdgcn_s_setprio(0);
}

// shared coalesced epilogue through sC (=sY reused) for the small GEMMs
__device__ __forceinline__ void small_gemm_epi(bf16_t* sC, bf16_t* __restrict__ O,
                                               const float* __restrict__ bias,
                                               const f32x4 acc[2][2],
                                               int m0, int n0, int wave, int lane,
                                               int tid)
{
  constexpr int TM = 32, TN = 128;
#pragma unroll
  for (int mi = 0; mi < 2; ++mi) {
#pragma unroll
    for (int ni = 0; ni < 2; ++ni) {
      const int col  = wave * 32 + ni * 16 + (lane & 15);
      const int row0 = mi * 16 + ((lane >> 4) << 2);
      const float bv = bias[n0 + col];
#pragma unroll
      for (int r = 0; r < 4; ++r)
        sC[(row0 + r) * TN + col] = __float2bfloat16(acc[mi][ni][r] + bv);
    }
  }
  __syncthreads();
#pragma unroll
  for (int p = 0; p < (TM * TN) / 2048; ++p) {   // 2 passes
    const int chunk = p * 256 + tid;
    const int rr = chunk / (TN / 8);
    const int cc = (chunk % (TN / 8)) * 8;
    *(uint4*)&O[(size_t)(m0 + rr) * D_ + n0 + cc] = *(const uint4*)&sC[rr * TN + cc];
  }
}

// ---------------------------------------------------------------------------
// Fused [x = Xin + sum_{z<4} PSPL; LN1; P1 = y@Wc + bc], layers 1..3.
// TM=32 rows, TN=128 cols; grid (B/32, 4) = 512 blocks, 256 thr.
// LDS: sY 32KB only. Two barriers total (post-prologue, pre-epilogue).
// blockIdx.y==0 writes Xout (ping-pong buffer, no race with Xin reads).
// ---------------------------------------------------------------------------
__launch_bounds__(256)
__global__ void lnfold_gemm(const float* __restrict__ Xin,
                            const bf16_t* __restrict__ P,
                            float* __restrict__ Xout,
                            const float* __restrict__ gamma,
                            const float* __restrict__ beta,
                            const bf16_t* __restrict__ Bt,   // WCT layer slice
                            const float* __restrict__ bias,  // BC layer slice
                            bf16_t* __restrict__ O)          // P1
{
  constexpr int TM = 32;
  __shared__ __align__(16) bf16_t sY[TM * D_];   // 32KB

  const int tid  = threadIdx.x;
  const int lane = tid & 63;
  const int wave = tid >> 6;
  const int m0   = blockIdx.x * TM;
  const int n0   = blockIdx.y * 128;
  const int c0   = lane * 8;

  // ---- prologue: fold partials + LN (swizzled store), 8 rows per wave ----
#pragma unroll
  for (int i = 0; i < 8; ++i) {
    const int row  = wave * 8 + i;
    const int grow = m0 + row;
    const float* xr = Xin + (size_t)grow * D_ + c0;
    float v[8];
    *(float4*)&v[0] = *(const float4*)&xr[0];
    *(float4*)&v[4] = *(const float4*)&xr[4];
#pragma unroll
    for (int z = 0; z < SPLITZ; ++z)
      fold_p(v, P + (size_t)z * B_ * D_ + (size_t)grow * D_ + c0);
    if (blockIdx.y == 0) {
      float* xo = Xout + (size_t)grow * D_ + c0;
      *(float4*)&xo[0] = *(const float4*)&v[0];
      *(float4*)&xo[4] = *(const float4*)&v[4];
    }
    ln_store_swz(v, gamma, beta, &sY[row * D_], row, lane);
  }
  __syncthreads();   // sY visible to all waves

  f32x4 acc[2][2];
#pragma unroll
  for (int mi = 0; mi < 2; ++mi)
#pragma unroll
    for (int ni = 0; ni < 2; ++ni)
      acc[mi][ni] = (f32x4){0.f, 0.f, 0.f, 0.f};

  small_gemm_loop(sY, Bt, n0, wave, lane, acc);

  __syncthreads();   // all sY reads done before reuse as sC
  small_gemm_epi(sY, O, bias, acc, m0, n0, wave, lane, tid);
}

// ---------------------------------------------------------------------------
// Fused step boundary + g1 (layer 0):
//  h = hsrc (+ fold PSPL if P); head(t-1) from h (if out, blockIdx.y==0);
//  x = emb_a + emb_b + h -> Xout (y==0); y = LN1_0(x) -> sY (swizzled);
//  P1 = y @ Wc0 + bc0.  Same geometry as lnfold_gemm.
// ---------------------------------------------------------------------------
__launch_bounds__(256)
__global__ void addln_gemm(const int* __restrict__ a_seq,
                           const int* __restrict__ b_seq,
                           const float* __restrict__ bit_emb,
                           const float* __restrict__ hsrc, int hstride,
                           const bf16_t* __restrict__ P,
                           float* __restrict__ Xout,
                           const float* __restrict__ gamma,
                           const float* __restrict__ beta,
                           const bf16_t* __restrict__ Bt,   // WCT layer 0
                           const float* __restrict__ bias,  // BC layer 0
                           bf16_t* __restrict__ O,          // P1
                           int t,
                           const float* __restrict__ hw,
                           const float* __restrict__ hb,
                           float* __restrict__ out)
{
  constexpr int TM = 32;
  __shared__ __align__(16) bf16_t sY[TM * D_];   // 32KB

  const int tid  = threadIdx.x;
  const int lane = tid & 63;
  const int wave = tid >> 6;
  const int m0   = blockIdx.x * TM;
  const int n0   = blockIdx.y * 128;
  const int c0   = lane * 8;

  const bool do_head = (out != nullptr) && (blockIdx.y == 0);
  float w[16];
  if (do_head) {
#pragma unroll
    for (int i = 0; i < 4; ++i)
      *(float4*)&w[i * 4] = *(const float4*)&hw[lane * 16 + i * 4];
  }

#pragma unroll
  for (int i = 0; i < 8; ++i) {
    const int row  = wave * 8 + i;
    const int grow = m0 + row;
    const int ai = a_seq[grow * S_ + t];
    const int bi = b_seq[grow * S_ + t];
    const float* pr = hsrc + (size_t)grow * hstride + c0;
    float p[8];
    *(float4*)&p[0] = *(const float4*)&pr[0];
    *(float4*)&p[4] = *(const float4*)&pr[4];
    if (P != nullptr) {
#pragma unroll
      for (int z = 0; z < SPLITZ; ++z)
        fold_p(p, P + (size_t)z * B_ * D_ + (size_t)grow * D_ + c0);
    }
    if (do_head) {
      float s0 = 0.f, s1 = 0.f;
#pragma unroll
      for (int j = 0; j < 8; ++j) { s0 += p[j] * w[2 * j]; s1 += p[j] * w[2 * j + 1]; }
#pragma unroll
      for (int o = 32; o; o >>= 1) { s0 += __shfl_xor(s0, o); s1 += __shfl_xor(s1, o); }
      if (lane == 0) {
        float* po = out + (size_t)grow * (S_ * 2) + (t - 1) * 2;
        po[0] = s0 + hb[0];
        po[1] = s1 + hb[1];
      }
    }
    float ea[8], eb[8], v[8];
    *(float4*)&ea[0] = *(const float4*)&bit_emb[ai * D_ + c0];
    *(float4*)&ea[4] = *(const float4*)&bit_emb[ai * D_ + c0 + 4];
    *(float4*)&eb[0] = *(const float4*)&bit_emb[bi * D_ + c0];
    *(float4*)&eb[4] = *(const float4*)&bit_emb[bi * D_ + c0 + 4];
#pragma unroll
    for (int j = 0; j < 8; ++j) v[j] = ea[j] + eb[j] + p[j];
    if (blockIdx.y == 0) {
      float* xo = Xout + (size_t)grow * D_ + c0;
      *(float4*)&xo[0] = *(const float4*)&v[0];
      *(float4*)&xo[4] = *(const float4*)&v[4];
    }
    ln_store_swz(v, gamma, beta, &sY[row * D_], row, lane);
  }
  __syncthreads();   // sY visible

  f32x4 acc[2][2];
#pragma unroll
  for (int mi = 0; mi < 2; ++mi)
#pragma unroll
    for (int ni = 0; ni < 2; ++ni)
      acc[mi][ni] = (f32x4){0.f, 0.f, 0.f, 0.f};

  small_gemm_loop(sY, Bt, n0, wave, lane, acc);

  __syncthreads();
  small_gemm_epi(sY, O, bias, acc, m0, n0, wave, lane, tid);
}

// Final head: h = X + P0..P3; logits[row, S-1, :] = h @ head_w + head_b.
__global__ void head_kernel(const float* __restrict__ X,
                            const bf16_t* __restrict__ P,
                            const float* __restrict__ hw,
                            const float* __restrict__ hb,
                            float* __restrict__ out, int t)
{
  const int row  = blockIdx.x * 4 + (threadIdx.x >> 6);
  const int lane = threadIdx.x & 63;
  const float* xr = X + (size_t)row * D_;
  const int c0 = lane * 8;
  float v[8];
  *(float4*)&v[0] = *(const float4*)&xr[c0];
  *(float4*)&v[4] = *(const float4*)&xr[c0 + 4];
#pragma unroll
  for (int z = 0; z < SPLITZ; ++z)
    fold_p(v, P + (size_t)z * B_ * D_ + (size_t)row * D_ + c0);
  float w[16];
#pragma unroll
  for (int i = 0; i < 4; ++i)
    *(float4*)&w[i * 4] = *(const float4*)&hw[lane * 16 + i * 4];
  float s0 = 0.f, s1 = 0.f;
#pragma unroll
  for (int i = 0; i < 8; ++i) { s0 += v[i] * w[2 * i]; s1 += v[i] * w[2 * i + 1]; }
#pragma unroll
  for (int o = 32; o; o >>= 1) { s0 += __shfl_xor(s0, o); s1 += __shfl_xor(s1, o); }
  if (lane == 0) {
    float* po = out + (size_t)row * (S_ * 2) + t * 2;
    po[0] = s0 + hb[0];
    po[1] = s1 + hb[1];
  }
}

// ---------------------------------------------------------------------------
// Prep kernels (run every launch; graph-safe)
// ---------------------------------------------------------------------------
__global__ void prep_wc(const float* __restrict__ qkv_w,
                        const float* __restrict__ out_w,
                        float* __restrict__ wc)
{
  const int n = blockIdx.x * 256 + threadIdx.x;
  const int k = blockIdx.y;
  const int l = blockIdx.z;
  const float* qrow = qkv_w + ((size_t)l * D_ + k) * (3 * D_) + 2 * D_;
  const float* ow   = out_w + (size_t)l * D_ * D_;
  float acc = 0.f;
  for (int j = 0; j < D_; ++j) acc += qrow[j] * ow[(size_t)j * D_ + n];
  wc[((size_t)l * D_ + k) * D_ + n] = acc;
}

__global__ void prep_bc(const float* __restrict__ qkv_b,
                        const float* __restrict__ out_w,
                        const float* __restrict__ out_b,
                        float* __restrict__ bc)
{
  const int l = blockIdx.x;
  const int n = threadIdx.x;
  const float* qb = qkv_b + (size_t)l * (3 * D_) + 2 * D_;
  const float* ow = out_w + (size_t)l * D_ * D_;
  float acc = out_b[(size_t)l * D_ + n];
  for (int j = 0; j < D_; ++j) acc += qb[j] * ow[(size_t)j * D_ + n];
  bc[(size_t)l * D_ + n] = acc;
}

// dst(C,R) bf16 = transpose(src(R,C) fp32), per-layer via blockIdx.z
__global__ void transpose_conv(const float* __restrict__ src,
                               bf16_t* __restrict__ dst, int R, int C)
{
  __shared__ float tile[32][33];
  const int l = blockIdx.z;
  const float* s = src + (size_t)l * R * C;
  bf16_t* d = dst + (size_t)l * R * C;
  const int c0 = blockIdx.x * 32, r0 = blockIdx.y * 32;
  const int tx = threadIdx.x, ty = threadIdx.y;
  tile[ty][tx] = s[(size_t)(r0 + ty) * C + (c0 + tx)];
  __syncthreads();
  d[(size_t)(c0 + ty) * R + (r0 + tx)] = __float2bfloat16(tile[tx][ty]);
}

// ---------------------------------------------------------------------------
extern "C" void kernel_launch(void* const* d_in, const int* in_sizes, int n_in,
                              void* d_out, int out_size, void* d_ws, size_t ws_size,
                              hipStream_t stream)
{
  const int*   a_seq     = (const int*)  d_in[0];
  const int*   b_seq     = (const int*)  d_in[1];
  const float* bit_emb   = (const float*)d_in[2];
  const float* start     = (const float*)d_in[3];
  const float* ln1_g     = (const float*)d_in[4];
  const float* ln1_b     = (const float*)d_in[5];
  const float* qkv_w     = (const float*)d_in[6];
  const float* qkv_b     = (const float*)d_in[7];
  const float* out_w     = (const float*)d_in[8];
  const float* out_b     = (const float*)d_in[9];
  const float* ln2_g     = (const float*)d_in[10];
  const float* ln2_b     = (const float*)d_in[11];
  const float* ff1_w     = (const float*)d_in[12];
  const float* ff1_b     = (const float*)d_in[13];
  const float* ff2_w     = (const float*)d_in[14];
  const float* ff2_b     = (const float*)d_in[15];
  const float* head_w    = (const float*)d_in[16];
  const float* head_b    = (const float*)d_in[17];
  float* out = (float*)d_out;

  // workspace layout
  char* ws = (char*)d_ws;
  float*  XA    = (float*) ws; ws += (size_t)B_ * D_ * 4;              // 8 MB
  float*  XB    = (float*) ws; ws += (size_t)B_ * D_ * 4;              // 8 MB
  bf16_t* Y     = (bf16_t*)ws; ws += (size_t)B_ * D_ * 2;              // 4 MB
  bf16_t* U     = (bf16_t*)ws; ws += (size_t)B_ * 4 * D_ * 2;          // 16 MB
  bf16_t* WCT   = (bf16_t*)ws; ws += (size_t)DEPTH_ * D_ * D_ * 2;     // 2 MB
  bf16_t* FF1T  = (bf16_t*)ws; ws += (size_t)DEPTH_ * D_ * 4 * D_ * 2; // 8 MB
  bf16_t* FF2T  = (bf16_t*)ws; ws += (size_t)DEPTH_ * 4 * D_ * D_ * 2; // 8 MB
  float*  BC    = (float*) ws; ws += (size_t)DEPTH_ * D_ * 4;          // 8 KB
  float*  WCTMP = (float*) ws; ws += (size_t)DEPTH_ * D_ * D_ * 4;     // 4 MB
  bf16_t* PSPL  = (bf16_t*)ws; ws += (size_t)SPLITZ * B_ * D_ * 2;     // 16 MB g3 split-K partials
  bf16_t* P1    = (bf16_t*)ws; ws += (size_t)B_ * D_ * 2;              // 4 MB g1 partial

  // ---- weight prep (per launch, identical every call) ----
  prep_wc<<<dim3(2, 512, 4), 256, 0, stream>>>(qkv_w, out_w, WCTMP);
  prep_bc<<<4, 512, 0, stream>>>(qkv_b, out_w, out_b, BC);
  transpose_conv<<<dim3(16, 16, 4),  dim3(32, 32), 0, stream>>>(WCTMP, WCT, 512, 512);
  transpose_conv<<<dim3(64, 16, 4),  dim3(32, 32), 0, stream>>>(ff1_w, FF1T, 512, 2048);
  transpose_conv<<<dim3(16, 64, 4),  dim3(32, 32), 0, stream>>>(ff2_w, FF2T, 2048, 512);

  // ---- recurrent steps ----
  // X ping-pong: addln XB->XA (l=0 residual base XA, ln_sum1 in-place),
  // lnfold l=1: XA->XB, l=2: XB->XA, l=3: XA->XB. Step ends on XB with
  // pending PSPL partials (folded by next addln / final head).
  for (int t = 0; t < S_; ++t) {
    if (t == 0)
      addln_gemm<<<dim3(B_ / 32, 4), 256, 0, stream>>>(
          a_seq, b_seq, bit_emb, start, 0, nullptr, XA,
          ln1_g, ln1_b, WCT, BC, P1, t, head_w, head_b, nullptr);
    else
      addln_gemm<<<dim3(B_ / 32, 4), 256, 0, stream>>>(
          a_seq, b_seq, bit_emb, XB, D_, PSPL, XA,
          ln1_g, ln1_b, WCT, BC, P1, t, head_w, head_b, out);
    float* cur = XA;
    float* alt = XB;
    for (int l = 0; l < DEPTH_; ++l) {
      if (l > 0) {
        // x = cur + fold(PSPL) -> alt ; y = LN1[l](x) ; P1 = y@Wc[l]+bc[l]
        lnfold_gemm<<<dim3(B_ / 32, 4), 256, 0, stream>>>(
            cur, PSPL, alt,
            ln1_g + (size_t)l * D_, ln1_b + (size_t)l * D_,
            WCT + (size_t)l * D_ * D_, BC + (size_t)l * D_, P1);
        float* tmp = cur; cur = alt; alt = tmp;
      }
      // x += P1 (in-place on cur) ; y = LN2[l](x)
      ln_sum1_kernel<<<B_ / 4, 256, 0, stream>>>(cur, P1,
                                                 ln2_g + (size_t)l * D_,
                                                 ln2_b + (size_t)l * D_, Y);
      // u = relu(y @ ff1[l] + b1)  (128x128, dbuf prefetch + T2 + T5)
      gemm_bf16<128, 128, 1, 1><<<dim3(32, 16), 256, 0, stream>>>(
          Y, FF1T + (size_t)l * D_ * 4 * D_, ff1_b + (size_t)l * 4 * D_, U,
          B_, 4 * D_, D_);
      // PSPL[z] = bf16(u @ ff2[l] (+b2 in z=0))  (128x128, split-K=4,
      //           dbuf prefetch + T2 + T5, grid (32,4,4)=512 blocks)
      gemm_bf16<128, 128, 2, SPLITZ><<<dim3(32, 4, SPLITZ), 256, 0, stream>>>(
          U, FF2T + (size_t)l * 4 * D_ * D_, ff2_b + (size_t)l * D_, PSPL,
          B_, D_, 4 * D_);
      // partials folded by next lnfold / addln / head
    }
    // invariant: cur == XB here (addln wrote XA; 3 lnfold swaps -> XB)
  }
  head_kernel<<<B_ / 4, 256, 0, stream>>>(XB, PSPL, head_w, head_b, out, S_ - 1);
}